// Round 15
// baseline (246.362 us; speedup 1.0000x reference)
//
#include <hip/hip_runtime.h>
#include <hip/hip_bf16.h>

#define HD 256
#define NN 32768
#define NE 262144
#define NB 128
#define NM 512
#define KADJ 48

typedef short bf16x8 __attribute__((ext_vector_type(8)));
typedef float f32x4 __attribute__((ext_vector_type(4)));
typedef unsigned short u16;
typedef unsigned short u16x8 __attribute__((ext_vector_type(8)));
typedef unsigned short u16x4 __attribute__((ext_vector_type(4)));

__device__ __forceinline__ float b2f(u16 u) {
    unsigned int i = ((unsigned int)u) << 16;
    float f; __builtin_memcpy(&f, &i, 4); return f;
}
__device__ __forceinline__ u16 f2b(float f) {
    unsigned int i; __builtin_memcpy(&i, &f, 4);
    return (u16)((i + 0x7FFFu + ((i >> 16) & 1u)) >> 16);
}

// ---------------- prep: transposes + pad zero + MFMA input projection + adjacency build ----------------
__global__ __launch_bounds__(256) void k_prep(const float* __restrict__ Wg1, const float* __restrict__ Wg2,
                                              const float* __restrict__ Wg3, const float* __restrict__ Wp1,
                                              u16* __restrict__ Ws1, u16* __restrict__ Ws2,
                                              u16* __restrict__ Ws3, u16* __restrict__ Wsa,
                                              u16* __restrict__ Wsb,
                                              const float* __restrict__ x, const int* __restrict__ player,
                                              const float* __restrict__ Win, const float* __restrict__ bin,
                                              u16* __restrict__ h0,
                                              const int* __restrict__ esrc, const int* __restrict__ edst,
                                              int* __restrict__ deg, int* __restrict__ adj,
                                              u16* __restrict__ p0, u16* __restrict__ p1, u16* __restrict__ p2) {
    __shared__ float smem[64 * 65];
    const int bid = blockIdx.x;
    const int tid = threadIdx.x;
    if (bid < 80) {
        float (*tile)[65] = (float (*)[65])smem;
        const int mid = bid >> 4, tb = bid & 15;
        const float* W; u16* D;
        switch (mid) {
            case 0: W = Wg1; D = Ws1; break;
            case 1: W = Wg2; D = Ws2; break;
            case 2: W = Wg3; D = Ws3; break;
            case 3: W = Wp1; D = Wsa; break;
            default: W = Wp1 + HD * HD; D = Wsb; break;
        }
        const int tk = tb >> 2, tn = tb & 3;
        const int c = tid & 63, r4 = tid >> 6;
#pragma unroll
        for (int r = 0; r < 16; r++) {
            int k = tk * 64 + r * 4 + r4;
            tile[r * 4 + r4][c] = W[(size_t)k * HD + tn * 64 + c];
        }
        __syncthreads();
#pragma unroll
        for (int r = 0; r < 16; r++) {
            int n = tn * 64 + r * 4 + r4;
            int k = tk * 64 + c;
            u16 val = f2b(tile[c][r * 4 + r4]);
            if (mid < 3) {
                int half = k >> 7;
                int c2 = ((k >> 3) & 15) ^ (n & 15);
                D[half * 32768 + n * 128 + c2 * 8 + (k & 7)] = val;
            } else {
                int cc = k >> 3;
                int c2 = (cc & 16) | ((cc & 15) ^ (n & 15));
                D[n * 256 + c2 * 8 + (k & 7)] = val;
            }
        }
    } else if (bid == 80) {
        if (tid < 96) {
            const int r = tid >> 5, c = tid & 31;
            u16* p = (r == 0) ? p0 : (r == 1) ? p1 : p2;
            u16x8 z = (u16x8){0, 0, 0, 0, 0, 0, 0, 0};
            *(u16x8*)(p + c * 8) = z;
        }
    } else if (bid < 337) {
        // ---- MFMA input projection ----
        const int lane = tid & 63, wvv = tid >> 6;
        const int l15 = lane & 15, lg = lane >> 4;
        const int node0 = (bid - 81) * 128;
        const int g = node0 >> 8;
        const int pl = player[g];

        bf16x8 wfr[16];
#pragma unroll
        for (int fc = 0; fc < 16; fc++) {
            const int n = fc * 16 + l15;
#pragma unroll
            for (int j = 0; j < 8; j++)
                wfr[fc][j] = (short)f2b(Win[(size_t)(lg * 8 + j) * HD + n]);
        }

#pragma unroll
        for (int grp = 0; grp < 2; grp++) {
            const int m = node0 + wvv * 32 + grp * 16 + l15;
            bf16x8 afr;
            {
                const float* xr = x + (size_t)m * 32 + lg * 8;
                f32x4 x0 = *(const f32x4*)xr;
                f32x4 x1 = *(const f32x4*)(xr + 4);
#pragma unroll
                for (int j = 0; j < 4; j++) afr[j] = (short)f2b(x0[j]);
#pragma unroll
                for (int j = 0; j < 4; j++) afr[4 + j] = (short)f2b(x1[j]);
            }
#pragma unroll
            for (int fc = 0; fc < 16; fc++) {
                f32x4 acc = (f32x4){0.f, 0.f, 0.f, 0.f};
                acc = __builtin_amdgcn_mfma_f32_16x16x32_bf16(wfr[fc], afr, acc, 0, 0, 0);
                const int cb = fc * 16 + lg * 4;
                f32x4 b4 = *(const f32x4*)(bin + cb);
                f32x4 w2 = *(const f32x4*)(Win + (size_t)(32 + pl) * HD + cb);
                u16x4 o;
#pragma unroll
                for (int e = 0; e < 4; e++) o[e] = f2b(acc[e] + b4[e] + w2[e]);
                *(u16x4*)(h0 + (size_t)m * HD + cb) = o;
            }
        }
    } else {
        const int e = (bid - 337) * 256 + tid;
        if (e < NE) {
            int d = edst[e];
            int p = atomicAdd(&deg[d], 1);
            if (p < KADJ) adj[d * KADJ + p] = esrc[e];
        }
    }
}

// ---------------- sort each node's adjacency slots (deterministic order) ----------------
__global__ __launch_bounds__(256) void k_sortadj(const int* __restrict__ deg, int* __restrict__ adj) {
    __shared__ int buf[256 * 49];
    const int n = blockIdx.x * 256 + threadIdx.x;
    int d = deg[n]; if (d > KADJ) d = KADJ;
    int* mine = &buf[threadIdx.x * 49];
    for (int i = 0; i < d; i++) mine[i] = adj[n * KADJ + i];
    for (int i = 1; i < d; i++) {
        int v = mine[i];
        int j = i - 1;
        while (j >= 0 && mine[j] > v) { mine[j + 1] = mine[j]; j--; }
        mine[j + 1] = v;
    }
    for (int i = 0; i < d; i++) adj[n * KADJ + i] = mine[i];
}

// ---------------- fused GIN layer: gather (regs, batched) + GEMM + bias + LN (+res) + ReLU ----------------
// 256 threads / 4 waves; 64 rows/block; grid 512; split-K W in 64KB LDS (2 blk/CU).
// Gather overlaps the async W staging; hin round-trip eliminated.
__global__ __launch_bounds__(256) void k_mmln(const u16* __restrict__ h, const int* __restrict__ deg,
                                              const int* __restrict__ adj, const u16* __restrict__ Wsw,
                                              const float* __restrict__ bias, const float* __restrict__ lng,
                                              const float* __restrict__ lnb, const u16* __restrict__ res,
                                              u16* __restrict__ hout) {
    const int tid = threadIdx.x;
    const int lane = tid & 63, wv = tid >> 6;
    const int l15 = lane & 15, lg = lane >> 4;
    const int m = blockIdx.x * 64 + wv * 16 + l15;

    __shared__ char Wl[65536];

    // stage W phase 0 (async; overlaps the gather below)
#pragma unroll
    for (int i = 0; i < 16; i++)
        __builtin_amdgcn_global_load_lds((const unsigned int*)(Wsw + tid * 8 + i * 2048),
                                         (unsigned int*)(Wl + tid * 16 + i * 4096), 16, 0, 0);

    // ---- gather self + neighbors into f32, batched 4 neighbors at a time ----
    // lane covers row m, 16B chunks at ks*32 + lg*8 for ks=0..7 (whole 512B row per 4 lanes)
    float vals[8][8];
    {
        const u16* hrow = h + (size_t)m * HD + lg * 8;
#pragma unroll
        for (int ks = 0; ks < 8; ks++) {
            u16x8 v = *(const u16x8*)(hrow + ks * 32);
#pragma unroll
            for (int j = 0; j < 8; j++) vals[ks][j] = b2f(v[j]);
        }
    }
    {
        int d = deg[m]; if (d > KADJ) d = KADJ;
        const int* arow = adj + m * KADJ;
        for (int e = 0; e < d; e += 4) {
            int idx[4];
#pragma unroll
            for (int k = 0; k < 4; k++) idx[k] = (e + k < d) ? arow[e + k] : NN;  // NN = zero row
            // 4 neighbors x 8 chunks, all independent loads
            u16x8 v[4][8];
#pragma unroll
            for (int k = 0; k < 4; k++) {
                const u16* srow = h + (size_t)idx[k] * HD + lg * 8;
#pragma unroll
                for (int ks = 0; ks < 8; ks++) v[k][ks] = *(const u16x8*)(srow + ks * 32);
            }
#pragma unroll
            for (int k = 0; k < 4; k++)
#pragma unroll
                for (int ks = 0; ks < 8; ks++)
#pragma unroll
                    for (int j = 0; j < 8; j++) vals[ks][j] += b2f(v[k][ks][j]);
        }
    }
    bf16x8 afr[8];
#pragma unroll
    for (int ks = 0; ks < 8; ks++)
#pragma unroll
        for (int j = 0; j < 8; j++) afr[ks][j] = (short)f2b(vals[ks][j]);

    f32x4 acc[16];
#pragma unroll
    for (int fc = 0; fc < 16; fc++) acc[fc] = (f32x4){0.f, 0.f, 0.f, 0.f};

    __syncthreads();
#pragma unroll
    for (int l = 0; l < 4; l++) {
#pragma unroll
        for (int fc = 0; fc < 16; fc++) {
            const int n = fc * 16 + l15;
            const int c2 = (l * 4 + lg) ^ l15;
            bf16x8 w = *(const bf16x8*)(Wl + n * 256 + c2 * 16);
            acc[fc] = __builtin_amdgcn_mfma_f32_16x16x32_bf16(w, afr[l], acc[fc], 0, 0, 0);
        }
    }
    __syncthreads();
#pragma unroll
    for (int i = 0; i < 16; i++)
        __builtin_amdgcn_global_load_lds((const unsigned int*)(Wsw + 32768 + tid * 8 + i * 2048),
                                         (unsigned int*)(Wl + tid * 16 + i * 4096), 16, 0, 0);
    __syncthreads();
#pragma unroll
    for (int l = 0; l < 4; l++) {
#pragma unroll
        for (int fc = 0; fc < 16; fc++) {
            const int n = fc * 16 + l15;
            const int c2 = (l * 4 + lg) ^ l15;
            bf16x8 w = *(const bf16x8*)(Wl + n * 256 + c2 * 16);
            acc[fc] = __builtin_amdgcn_mfma_f32_16x16x32_bf16(w, afr[4 + l], acc[fc], 0, 0, 0);
        }
    }

    float s = 0.f, q = 0.f;
#pragma unroll
    for (int fc = 0; fc < 16; fc++) {
        f32x4 b4 = *(const f32x4*)(bias + fc * 16 + lg * 4);
#pragma unroll
        for (int e = 0; e < 4; e++) {
            float z = acc[fc][e] + b4[e];
            acc[fc][e] = z;
            s += z; q += z * z;
        }
    }
    s += __shfl_xor(s, 16); s += __shfl_xor(s, 32);
    q += __shfl_xor(q, 16); q += __shfl_xor(q, 32);
    const float mean = s * (1.0f / HD);
    const float rinv = rsqrtf(q * (1.0f / HD) - mean * mean + 1e-5f);

    const bool hasRes = (res != nullptr);
#pragma unroll
    for (int fc = 0; fc < 16; fc++) {
        f32x4 g4 = *(const f32x4*)(lng + fc * 16 + lg * 4);
        f32x4 e4 = *(const f32x4*)(lnb + fc * 16 + lg * 4);
        float y[4];
#pragma unroll
        for (int e = 0; e < 4; e++) y[e] = (acc[fc][e] - mean) * rinv * g4[e] + e4[e];
        if (hasRes) {
            u16x4 r = *(const u16x4*)(res + (size_t)m * HD + fc * 16 + lg * 4);
#pragma unroll
            for (int e = 0; e < 4; e++) y[e] += b2f(r[e]);
        }
        u16x4 o;
#pragma unroll
        for (int e = 0; e < 4; e++) o[e] = f2b(fmaxf(y[e], 0.f));
        *(u16x4*)(hout + (size_t)m * HD + fc * 16 + lg * 4) = o;
    }
}

// ---------------- pool/value head (blocks 0..127) + dense GEMM (blocks 128..1151) ----------------
__global__ __launch_bounds__(512) void k_densepv(const u16* __restrict__ h,
                                                 const u16* __restrict__ Wsa, const u16* __restrict__ Wsb,
                                                 const float* __restrict__ bp1,
                                                 u16* __restrict__ hP1, u16* __restrict__ hP2,
                                                 const float* __restrict__ W1, const float* __restrict__ b1,
                                                 const float* __restrict__ W2, const float* __restrict__ b2p,
                                                 const float* __restrict__ g1, const float* __restrict__ be1,
                                                 const float* __restrict__ m1, const float* __restrict__ v1,
                                                 const float* __restrict__ g2, const float* __restrict__ be2,
                                                 const float* __restrict__ m2, const float* __restrict__ v2,
                                                 const float* __restrict__ Wv, const float* __restrict__ bv,
                                                 float* __restrict__ vout) {
    __shared__ char sm[65536];
    const int tid = threadIdx.x;
    const int lane = tid & 63, wv = tid >> 6;
    const int bid = blockIdx.x;
    if (bid >= 128) {
        const int db = bid - 128;
        const int l15 = lane & 15, lg = lane >> 4;
        const int wsel = db >> 9, rem = db & 511;
        const int ch = rem >> 8, rb = rem & 255;
        const int m = rb * 128 + wv * 16 + l15;
        const u16* Wsw = (wsel ? Wsb : Wsa) + ch * 128 * 256;
        u16* outp = wsel ? hP2 : hP1;
        char* Wl = sm;

#pragma unroll
        for (int i = 0; i < 8; i++)
            __builtin_amdgcn_global_load_lds((const unsigned int*)(Wsw + tid * 8 + i * 4096),
                                             (unsigned int*)(Wl + tid * 16 + i * 8192), 16, 0, 0);

        bf16x8 afr[8];
        {
            const u16* hrow = h + (size_t)m * HD;
#pragma unroll
            for (int ks = 0; ks < 8; ks++) afr[ks] = *(const bf16x8*)(hrow + ks * 32 + lg * 8);
        }

        __syncthreads();

        f32x4 acc[8];
#pragma unroll
        for (int fc = 0; fc < 8; fc++) acc[fc] = (f32x4){0.f, 0.f, 0.f, 0.f};
#pragma unroll
        for (int ks = 0; ks < 8; ks++) {
#pragma unroll
            for (int fc = 0; fc < 8; fc++) {
                const int c = ks * 4 + lg;
                const int c2 = (c & 16) | ((c & 15) ^ l15);
                bf16x8 w = *(const bf16x8*)(Wl + (fc * 16 + l15) * 512 + c2 * 16);
                acc[fc] = __builtin_amdgcn_mfma_f32_16x16x32_bf16(w, afr[ks], acc[fc], 0, 0, 0);
            }
        }

#pragma unroll
        for (int fc = 0; fc < 8; fc++) {
            float b4[4] = {0.f, 0.f, 0.f, 0.f};
            if (!wsel) {
                f32x4 bb = *(const f32x4*)(bp1 + ch * 128 + fc * 16 + lg * 4);
#pragma unroll
                for (int e = 0; e < 4; e++) b4[e] = bb[e];
            }
            u16x4 o;
#pragma unroll
            for (int e = 0; e < 4; e++) o[e] = f2b(acc[fc][e] + b4[e]);
            *(u16x4*)(outp + (size_t)m * HD + ch * 128 + fc * 16 + lg * 4) = o;
        }
    } else {
        const int g = bid;
        float (*pool)[256] = (float (*)[256])sm;
        float* buf = (float*)(sm + 8192);
        float (*part)[256] = (float (*)[256])(sm + 8192 + 1024);
        float* red = (float*)(sm + 8192 + 1024 + 2048);
        {
            float a0 = 0.f, a1 = 0.f, a2 = 0.f, a3 = 0.f;
            const u16* base = h + ((size_t)g * 256 + wv * 32) * HD + lane * 4;
#pragma unroll 8
            for (int i = 0; i < 32; i++) {
                u16x4 v = *(const u16x4*)(base + (size_t)i * HD);
                a0 += b2f(v[0]); a1 += b2f(v[1]); a2 += b2f(v[2]); a3 += b2f(v[3]);
            }
            pool[wv][lane * 4 + 0] = a0; pool[wv][lane * 4 + 1] = a1;
            pool[wv][lane * 4 + 2] = a2; pool[wv][lane * 4 + 3] = a3;
        }
        __syncthreads();
        const int jj = tid & 255, kh = tid >> 8;
        if (tid < 256) {
            float s = 0.f;
#pragma unroll
            for (int w = 0; w < 8; w++) s += pool[w][tid];
            buf[tid] = s * (1.0f / 256.0f);
        }
        __syncthreads();
        {
            const float* Wcol = W1 + (size_t)(kh * 128) * HD + jj;
            const float* bk = buf + kh * 128;
            float p0 = 0.f, p1 = 0.f, p2 = 0.f, p3 = 0.f;
#pragma unroll
            for (int k = 0; k < 128; k += 4) {
                p0 += bk[k + 0] * Wcol[(size_t)(k + 0) * HD];
                p1 += bk[k + 1] * Wcol[(size_t)(k + 1) * HD];
                p2 += bk[k + 2] * Wcol[(size_t)(k + 2) * HD];
                p3 += bk[k + 3] * Wcol[(size_t)(k + 3) * HD];
            }
            part[kh][jj] = (p0 + p1) + (p2 + p3);
        }
        __syncthreads();
        if (tid < 256) {
            float z = part[0][tid] + part[1][tid] + b1[tid];
            z = (z - m1[tid]) * rsqrtf(v1[tid] + 1e-5f) * g1[tid] + be1[tid];
            buf[tid] = fmaxf(z, 0.f);
        }
        __syncthreads();
        {
            const float* Wcol = W2 + (size_t)(kh * 128) * HD + jj;
            const float* bk = buf + kh * 128;
            float p0 = 0.f, p1 = 0.f, p2 = 0.f, p3 = 0.f;
#pragma unroll
            for (int k = 0; k < 128; k += 4) {
                p0 += bk[k + 0] * Wcol[(size_t)(k + 0) * HD];
                p1 += bk[k + 1] * Wcol[(size_t)(k + 1) * HD];
                p2 += bk[k + 2] * Wcol[(size_t)(k + 2) * HD];
                p3 += bk[k + 3] * Wcol[(size_t)(k + 3) * HD];
            }
            part[kh][jj] = (p0 + p1) + (p2 + p3);
        }
        __syncthreads();
        float pv = 0.f;
        if (tid < 256) {
            float z2 = part[0][tid] + part[1][tid] + b2p[tid];
            z2 = (z2 - m2[tid]) * rsqrtf(v2[tid] + 1e-5f) * g2[tid] + be2[tid];
            z2 = fmaxf(z2, 0.f);
            pv = z2 * Wv[tid];
        }
#pragma unroll
        for (int mm = 1; mm < 64; mm <<= 1) pv += __shfl_xor(pv, mm, 64);
        if (tid < 256 && (tid & 63) == 0) red[tid >> 6] = pv;
        __syncthreads();
        if (tid == 0) vout[g] = tanhf(red[0] + red[1] + red[2] + red[3] + bv[0]);
    }
}

// ---------------- per-move: 8 lanes per move row; coalesced; shfl reduce ----------------
__global__ __launch_bounds__(256) void k_moves(const u16* __restrict__ hP1, const u16* __restrict__ hP2,
                                               const float* __restrict__ wp2, const float* __restrict__ bp2,
                                               const int* __restrict__ mov, float* __restrict__ out) {
    __shared__ float wp2L[256];
    wp2L[threadIdx.x] = wp2[threadIdx.x];
    __syncthreads();
    const int wv = threadIdx.x >> 6, lane = threadIdx.x & 63;
    const int grp = lane >> 3, li = lane & 7;
    const int mi = blockIdx.x * 32 + wv * 8 + grp;
    int a = mov[(size_t)mi * 2], b = mov[(size_t)mi * 2 + 1];
    const bool vld = (a != -1) && (b != -1);
    const int s = a < 0 ? 0 : a, t = b < 0 ? 0 : b;
    const u16* r1 = hP1 + (size_t)s * HD + li * 32;
    const u16* r2 = hP2 + (size_t)t * HD + li * 32;
    float acc = 0.f;
#pragma unroll
    for (int c = 0; c < 4; c++) {
        u16x8 v1 = *(const u16x8*)(r1 + c * 8);
        u16x8 v2 = *(const u16x8*)(r2 + c * 8);
#pragma unroll
        for (int j = 0; j < 8; j++) {
            float z = b2f(v1[j]) + b2f(v2[j]);
            acc += fmaxf(z, 0.f) * wp2L[li * 32 + c * 8 + j];
        }
    }
    acc += __shfl_xor(acc, 1); acc += __shfl_xor(acc, 2); acc += __shfl_xor(acc, 4);
    if (li == 0) out[mi] = vld ? acc + bp2[0] : -1e9f;
}

extern "C" void kernel_launch(void* const* d_in, const int* in_sizes, int n_in,
                              void* d_out, int out_size, void* d_ws, size_t ws_size,
                              hipStream_t stream) {
    const float* x    = (const float*)d_in[0];
    const int* eidx   = (const int*)d_in[1];
    const int* mov    = (const int*)d_in[2];
    const int* player = (const int*)d_in[3];
    const float* Win  = (const float*)d_in[5];
    const float* b_in = (const float*)d_in[6];
    const float* Wg1 = (const float*)d_in[7],  *bg1 = (const float*)d_in[8];
    const float* Wg2 = (const float*)d_in[9],  *bg2 = (const float*)d_in[10];
    const float* Wg3 = (const float*)d_in[11], *bg3 = (const float*)d_in[12];
    const float* ln1g = (const float*)d_in[13], *ln1b = (const float*)d_in[14];
    const float* ln2g = (const float*)d_in[15], *ln2b = (const float*)d_in[16];
    const float* ln3g = (const float*)d_in[17], *ln3b = (const float*)d_in[18];
    const float* Wfc1 = (const float*)d_in[19], *bfc1 = (const float*)d_in[20];
    const float* Wfc2 = (const float*)d_in[21], *bfc2 = (const float*)d_in[22];
    const float* bn1g = (const float*)d_in[23], *bn1b = (const float*)d_in[24];
    const float* bn1m = (const float*)d_in[25], *bn1v = (const float*)d_in[26];
    const float* bn2g = (const float*)d_in[27], *bn2b = (const float*)d_in[28];
    const float* bn2m = (const float*)d_in[29], *bn2v = (const float*)d_in[30];
    const float* Wp1 = (const float*)d_in[31], *bp1 = (const float*)d_in[32];
    const float* Wp2 = (const float*)d_in[33], *bp2 = (const float*)d_in[34];
    const float* Wv  = (const float*)d_in[35], *bv  = (const float*)d_in[36];

    char* ws = (char*)d_ws;
    size_t off = 0;
    auto alloc = [&](size_t bytes) {
        size_t p = off;
        off = (off + bytes + 255) & ~(size_t)255;
        return (void*)(ws + p);
    };
    u16* h0   = (u16*)alloc((size_t)(NN + 8) * HD * 2);
    u16* hA   = (u16*)alloc((size_t)(NN + 8) * HD * 2);
    u16* hB   = (u16*)alloc((size_t)(NN + 8) * HD * 2);
    u16* Ws1  = (u16*)alloc((size_t)HD * HD * 2);
    u16* Ws2  = (u16*)alloc((size_t)HD * HD * 2);
    u16* Ws3  = (u16*)alloc((size_t)HD * HD * 2);
    u16* Wsa  = (u16*)alloc((size_t)HD * HD * 2);
    u16* Wsb  = (u16*)alloc((size_t)HD * HD * 2);
    int* deg  = (int*)alloc((size_t)NN * 4);
    int* adj  = (int*)alloc((size_t)NN * KADJ * 4);

    const int* esrc = eidx;
    const int* edst = eidx + NE;

    hipMemsetAsync(deg, 0, (size_t)NN * 4, stream);
    k_prep<<<1361, 256, 0, stream>>>(Wg1, Wg2, Wg3, Wp1, Ws1, Ws2, Ws3, Wsa, Wsb,
                                     x, player, Win, b_in, h0, esrc, edst, deg, adj,
                                     h0 + (size_t)NN * HD, hA + (size_t)NN * HD, hB + (size_t)NN * HD);
    k_sortadj<<<NN / 256, 256, 0, stream>>>(deg, adj);

    // fused GIN layers (gather + GEMM + LN)
    k_mmln<<<NN / 64, 256, 0, stream>>>(h0, deg, adj, Ws1, bg1, ln1g, ln1b, nullptr, hA);
    k_mmln<<<NN / 64, 256, 0, stream>>>(hA, deg, adj, Ws2, bg2, ln2g, ln2b, nullptr, hB);
    k_mmln<<<NN / 64, 256, 0, stream>>>(hB, deg, adj, Ws3, bg3, ln3g, ln3b, h0, hA);

    // h0, hB dead -> reuse for policy precompute
    u16* hP1 = h0;
    u16* hP2 = hB;

    k_densepv<<<1152, 512, 0, stream>>>(hA, Wsa, Wsb, bp1, hP1, hP2,
                                        Wfc1, bfc1, Wfc2, bfc2,
                                        bn1g, bn1b, bn1m, bn1v, bn2g, bn2b, bn2m, bn2v,
                                        Wv, bv, ((float*)d_out) + NB * NM);
    k_moves<<<(NB * NM) / 32, 256, 0, stream>>>(hP1, hP2, Wp2, bp2, mov, (float*)d_out);
}

// Round 16
// 207.109 us; speedup vs baseline: 1.1895x; 1.1895x over previous
//
#include <hip/hip_runtime.h>
#include <hip/hip_bf16.h>

#define HD 256
#define NN 32768
#define NE 262144
#define NB 128
#define NM 512
#define KADJ 48

typedef short bf16x8 __attribute__((ext_vector_type(8)));
typedef float f32x4 __attribute__((ext_vector_type(4)));
typedef unsigned short u16;
typedef unsigned short u16x8 __attribute__((ext_vector_type(8)));
typedef unsigned short u16x4 __attribute__((ext_vector_type(4)));

__device__ __forceinline__ float b2f(u16 u) {
    unsigned int i = ((unsigned int)u) << 16;
    float f; __builtin_memcpy(&f, &i, 4); return f;
}
__device__ __forceinline__ u16 f2b(float f) {
    unsigned int i; __builtin_memcpy(&i, &f, 4);
    return (u16)((i + 0x7FFFu + ((i >> 16) & 1u)) >> 16);
}

// ---------------- prep: transposes + pad zero + MFMA input projection + adjacency build ----------------
__global__ __launch_bounds__(256) void k_prep(const float* __restrict__ Wg1, const float* __restrict__ Wg2,
                                              const float* __restrict__ Wg3, const float* __restrict__ Wp1,
                                              u16* __restrict__ Ws1, u16* __restrict__ Ws2,
                                              u16* __restrict__ Ws3, u16* __restrict__ Wsa,
                                              u16* __restrict__ Wsb,
                                              const float* __restrict__ x, const int* __restrict__ player,
                                              const float* __restrict__ Win, const float* __restrict__ bin,
                                              u16* __restrict__ h0,
                                              const int* __restrict__ esrc, const int* __restrict__ edst,
                                              int* __restrict__ deg, int* __restrict__ adj,
                                              u16* __restrict__ p0, u16* __restrict__ p1, u16* __restrict__ p2) {
    __shared__ float smem[64 * 65];
    const int bid = blockIdx.x;
    const int tid = threadIdx.x;
    if (bid < 80) {
        float (*tile)[65] = (float (*)[65])smem;
        const int mid = bid >> 4, tb = bid & 15;
        const float* W; u16* D;
        switch (mid) {
            case 0: W = Wg1; D = Ws1; break;
            case 1: W = Wg2; D = Ws2; break;
            case 2: W = Wg3; D = Ws3; break;
            case 3: W = Wp1; D = Wsa; break;
            default: W = Wp1 + HD * HD; D = Wsb; break;
        }
        const int tk = tb >> 2, tn = tb & 3;
        const int c = tid & 63, r4 = tid >> 6;
#pragma unroll
        for (int r = 0; r < 16; r++) {
            int k = tk * 64 + r * 4 + r4;
            tile[r * 4 + r4][c] = W[(size_t)k * HD + tn * 64 + c];
        }
        __syncthreads();
#pragma unroll
        for (int r = 0; r < 16; r++) {
            int n = tn * 64 + r * 4 + r4;
            int k = tk * 64 + c;
            u16 val = f2b(tile[c][r * 4 + r4]);
            if (mid < 3) {
                int half = k >> 7;
                int c2 = ((k >> 3) & 15) ^ (n & 15);
                D[half * 32768 + n * 128 + c2 * 8 + (k & 7)] = val;
            } else {
                int cc = k >> 3;
                int c2 = (cc & 16) | ((cc & 15) ^ (n & 15));
                D[n * 256 + c2 * 8 + (k & 7)] = val;
            }
        }
    } else if (bid == 80) {
        if (tid < 96) {
            const int r = tid >> 5, c = tid & 31;
            u16* p = (r == 0) ? p0 : (r == 1) ? p1 : p2;
            u16x8 z = (u16x8){0, 0, 0, 0, 0, 0, 0, 0};
            *(u16x8*)(p + c * 8) = z;
        }
    } else if (bid < 337) {
        // ---- MFMA input projection ----
        const int lane = tid & 63, wvv = tid >> 6;
        const int l15 = lane & 15, lg = lane >> 4;
        const int node0 = (bid - 81) * 128;
        const int g = node0 >> 8;
        const int pl = player[g];

        bf16x8 wfr[16];
#pragma unroll
        for (int fc = 0; fc < 16; fc++) {
            const int n = fc * 16 + l15;
#pragma unroll
            for (int j = 0; j < 8; j++)
                wfr[fc][j] = (short)f2b(Win[(size_t)(lg * 8 + j) * HD + n]);
        }

#pragma unroll
        for (int grp = 0; grp < 2; grp++) {
            const int m = node0 + wvv * 32 + grp * 16 + l15;
            bf16x8 afr;
            {
                const float* xr = x + (size_t)m * 32 + lg * 8;
                f32x4 x0 = *(const f32x4*)xr;
                f32x4 x1 = *(const f32x4*)(xr + 4);
#pragma unroll
                for (int j = 0; j < 4; j++) afr[j] = (short)f2b(x0[j]);
#pragma unroll
                for (int j = 0; j < 4; j++) afr[4 + j] = (short)f2b(x1[j]);
            }
#pragma unroll
            for (int fc = 0; fc < 16; fc++) {
                f32x4 acc = (f32x4){0.f, 0.f, 0.f, 0.f};
                acc = __builtin_amdgcn_mfma_f32_16x16x32_bf16(wfr[fc], afr, acc, 0, 0, 0);
                const int cb = fc * 16 + lg * 4;
                f32x4 b4 = *(const f32x4*)(bin + cb);
                f32x4 w2 = *(const f32x4*)(Win + (size_t)(32 + pl) * HD + cb);
                u16x4 o;
#pragma unroll
                for (int e = 0; e < 4; e++) o[e] = f2b(acc[e] + b4[e] + w2[e]);
                *(u16x4*)(h0 + (size_t)m * HD + cb) = o;
            }
        }
    } else {
        const int e = (bid - 337) * 256 + tid;
        if (e < NE) {
            int d = edst[e];
            int p = atomicAdd(&deg[d], 1);
            if (p < KADJ) adj[d * KADJ + p] = esrc[e];
        }
    }
}

// ---------------- aggregation: 32 lanes/node x 16B, batch-8 independent row loads ----------------
// doSort=1 (layer 1): canonical-sort each node's adj row in LDS, write back for layers 2/3.
__global__ __launch_bounds__(256) void k_agg(const u16* __restrict__ h, const int* __restrict__ deg,
                                             int* __restrict__ adj, u16* __restrict__ hin, int doSort) {
    __shared__ int sbuf[8][KADJ];
    const int grp = threadIdx.x >> 5;
    const int n = blockIdx.x * 8 + grp;
    const int li = threadIdx.x & 31;
    const int fo = li * 8;
    int d = deg[n]; if (d > KADJ) d = KADJ;
    int* arow = adj + n * KADJ;

    if (doSort) {
        for (int i = li; i < d; i += 32) sbuf[grp][i] = arow[i];
        __syncthreads();
        if (li == 0) {
            for (int i = 1; i < d; i++) {
                int v = sbuf[grp][i];
                int j = i - 1;
                while (j >= 0 && sbuf[grp][j] > v) { sbuf[grp][j + 1] = sbuf[grp][j]; j--; }
                sbuf[grp][j + 1] = v;
            }
        }
        __syncthreads();
        for (int i = li; i < d; i += 32) arow[i] = sbuf[grp][i];
    }

    const u16* hp = h + fo;
    u16x8 sv = *(const u16x8*)(hp + (size_t)n * HD);
    float a[8];
#pragma unroll
    for (int j = 0; j < 8; j++) a[j] = b2f(sv[j]);
    for (int e = 0; e < d; e += 8) {
        int idx[8];
#pragma unroll
        for (int k = 0; k < 8; k++)
            idx[k] = (e + k < d) ? (doSort ? sbuf[grp][e + k] : arow[e + k]) : NN;
        u16x8 v[8];
#pragma unroll
        for (int k = 0; k < 8; k++) v[k] = *(const u16x8*)(hp + (size_t)idx[k] * HD);
#pragma unroll
        for (int k = 0; k < 8; k++)
#pragma unroll
            for (int j = 0; j < 8; j++) a[j] += b2f(v[k][j]);
    }
    u16x8 o;
#pragma unroll
    for (int j = 0; j < 8; j++) o[j] = f2b(a[j]);
    *(u16x8*)(hin + (size_t)n * HD + fo) = o;
}

// ---------------- GEMM + bias + LN (+res) + ReLU; split-K, 64KB LDS, 2 blk/CU ----------------
__global__ __launch_bounds__(256) void k_mmln(const u16* __restrict__ hin, const u16* __restrict__ Wsw,
                                              const float* __restrict__ bias, const float* __restrict__ lng,
                                              const float* __restrict__ lnb, const u16* __restrict__ res,
                                              u16* __restrict__ hout) {
    const int tid = threadIdx.x;
    const int lane = tid & 63, wv = tid >> 6;
    const int l15 = lane & 15, lg = lane >> 4;
    const int m = blockIdx.x * 64 + wv * 16 + l15;

    __shared__ char Wl[65536];

#pragma unroll
    for (int i = 0; i < 16; i++)
        __builtin_amdgcn_global_load_lds((const unsigned int*)(Wsw + tid * 8 + i * 2048),
                                         (unsigned int*)(Wl + tid * 16 + i * 4096), 16, 0, 0);

    bf16x8 afr[8];
    {
        const u16* hrow = hin + (size_t)m * HD;
#pragma unroll
        for (int ks = 0; ks < 8; ks++) afr[ks] = *(const bf16x8*)(hrow + ks * 32 + lg * 8);
    }

    f32x4 acc[16];
#pragma unroll
    for (int fc = 0; fc < 16; fc++) acc[fc] = (f32x4){0.f, 0.f, 0.f, 0.f};

    __syncthreads();
#pragma unroll
    for (int l = 0; l < 4; l++) {
#pragma unroll
        for (int fc = 0; fc < 16; fc++) {
            const int n = fc * 16 + l15;
            const int c2 = (l * 4 + lg) ^ l15;
            bf16x8 w = *(const bf16x8*)(Wl + n * 256 + c2 * 16);
            acc[fc] = __builtin_amdgcn_mfma_f32_16x16x32_bf16(w, afr[l], acc[fc], 0, 0, 0);
        }
    }
    __syncthreads();
#pragma unroll
    for (int i = 0; i < 16; i++)
        __builtin_amdgcn_global_load_lds((const unsigned int*)(Wsw + 32768 + tid * 8 + i * 2048),
                                         (unsigned int*)(Wl + tid * 16 + i * 4096), 16, 0, 0);
    __syncthreads();
#pragma unroll
    for (int l = 0; l < 4; l++) {
#pragma unroll
        for (int fc = 0; fc < 16; fc++) {
            const int n = fc * 16 + l15;
            const int c2 = (l * 4 + lg) ^ l15;
            bf16x8 w = *(const bf16x8*)(Wl + n * 256 + c2 * 16);
            acc[fc] = __builtin_amdgcn_mfma_f32_16x16x32_bf16(w, afr[4 + l], acc[fc], 0, 0, 0);
        }
    }

    float s = 0.f, q = 0.f;
#pragma unroll
    for (int fc = 0; fc < 16; fc++) {
        f32x4 b4 = *(const f32x4*)(bias + fc * 16 + lg * 4);
#pragma unroll
        for (int e = 0; e < 4; e++) {
            float z = acc[fc][e] + b4[e];
            acc[fc][e] = z;
            s += z; q += z * z;
        }
    }
    s += __shfl_xor(s, 16); s += __shfl_xor(s, 32);
    q += __shfl_xor(q, 16); q += __shfl_xor(q, 32);
    const float mean = s * (1.0f / HD);
    const float rinv = rsqrtf(q * (1.0f / HD) - mean * mean + 1e-5f);

    const bool hasRes = (res != nullptr);
#pragma unroll
    for (int fc = 0; fc < 16; fc++) {
        f32x4 g4 = *(const f32x4*)(lng + fc * 16 + lg * 4);
        f32x4 e4 = *(const f32x4*)(lnb + fc * 16 + lg * 4);
        float y[4];
#pragma unroll
        for (int e = 0; e < 4; e++) y[e] = (acc[fc][e] - mean) * rinv * g4[e] + e4[e];
        if (hasRes) {
            u16x4 r = *(const u16x4*)(res + (size_t)m * HD + fc * 16 + lg * 4);
#pragma unroll
            for (int e = 0; e < 4; e++) y[e] += b2f(r[e]);
        }
        u16x4 o;
#pragma unroll
        for (int e = 0; e < 4; e++) o[e] = f2b(fmaxf(y[e], 0.f));
        *(u16x4*)(hout + (size_t)m * HD + fc * 16 + lg * 4) = o;
    }
}

// ---------------- pool/value head (blocks 0..127) + dense GEMM (blocks 128..1151) ----------------
__global__ __launch_bounds__(512) void k_densepv(const u16* __restrict__ h,
                                                 const u16* __restrict__ Wsa, const u16* __restrict__ Wsb,
                                                 const float* __restrict__ bp1,
                                                 u16* __restrict__ hP1, u16* __restrict__ hP2,
                                                 const float* __restrict__ W1, const float* __restrict__ b1,
                                                 const float* __restrict__ W2, const float* __restrict__ b2p,
                                                 const float* __restrict__ g1, const float* __restrict__ be1,
                                                 const float* __restrict__ m1, const float* __restrict__ v1,
                                                 const float* __restrict__ g2, const float* __restrict__ be2,
                                                 const float* __restrict__ m2, const float* __restrict__ v2,
                                                 const float* __restrict__ Wv, const float* __restrict__ bv,
                                                 float* __restrict__ vout) {
    __shared__ char sm[65536];
    const int tid = threadIdx.x;
    const int lane = tid & 63, wv = tid >> 6;
    const int bid = blockIdx.x;
    if (bid >= 128) {
        const int db = bid - 128;
        const int l15 = lane & 15, lg = lane >> 4;
        const int wsel = db >> 9, rem = db & 511;
        const int ch = rem >> 8, rb = rem & 255;
        const int m = rb * 128 + wv * 16 + l15;
        const u16* Wsw = (wsel ? Wsb : Wsa) + ch * 128 * 256;
        u16* outp = wsel ? hP2 : hP1;
        char* Wl = sm;

#pragma unroll
        for (int i = 0; i < 8; i++)
            __builtin_amdgcn_global_load_lds((const unsigned int*)(Wsw + tid * 8 + i * 4096),
                                             (unsigned int*)(Wl + tid * 16 + i * 8192), 16, 0, 0);

        bf16x8 afr[8];
        {
            const u16* hrow = h + (size_t)m * HD;
#pragma unroll
            for (int ks = 0; ks < 8; ks++) afr[ks] = *(const bf16x8*)(hrow + ks * 32 + lg * 8);
        }

        __syncthreads();

        f32x4 acc[8];
#pragma unroll
        for (int fc = 0; fc < 8; fc++) acc[fc] = (f32x4){0.f, 0.f, 0.f, 0.f};
#pragma unroll
        for (int ks = 0; ks < 8; ks++) {
#pragma unroll
            for (int fc = 0; fc < 8; fc++) {
                const int c = ks * 4 + lg;
                const int c2 = (c & 16) | ((c & 15) ^ l15);
                bf16x8 w = *(const bf16x8*)(Wl + (fc * 16 + l15) * 512 + c2 * 16);
                acc[fc] = __builtin_amdgcn_mfma_f32_16x16x32_bf16(w, afr[ks], acc[fc], 0, 0, 0);
            }
        }

#pragma unroll
        for (int fc = 0; fc < 8; fc++) {
            float b4[4] = {0.f, 0.f, 0.f, 0.f};
            if (!wsel) {
                f32x4 bb = *(const f32x4*)(bp1 + ch * 128 + fc * 16 + lg * 4);
#pragma unroll
                for (int e = 0; e < 4; e++) b4[e] = bb[e];
            }
            u16x4 o;
#pragma unroll
            for (int e = 0; e < 4; e++) o[e] = f2b(acc[fc][e] + b4[e]);
            *(u16x4*)(outp + (size_t)m * HD + ch * 128 + fc * 16 + lg * 4) = o;
        }
    } else {
        const int g = bid;
        float (*pool)[256] = (float (*)[256])sm;
        float* buf = (float*)(sm + 8192);
        float (*part)[256] = (float (*)[256])(sm + 8192 + 1024);
        float* red = (float*)(sm + 8192 + 1024 + 2048);
        {
            float a0 = 0.f, a1 = 0.f, a2 = 0.f, a3 = 0.f;
            const u16* base = h + ((size_t)g * 256 + wv * 32) * HD + lane * 4;
#pragma unroll 8
            for (int i = 0; i < 32; i++) {
                u16x4 v = *(const u16x4*)(base + (size_t)i * HD);
                a0 += b2f(v[0]); a1 += b2f(v[1]); a2 += b2f(v[2]); a3 += b2f(v[3]);
            }
            pool[wv][lane * 4 + 0] = a0; pool[wv][lane * 4 + 1] = a1;
            pool[wv][lane * 4 + 2] = a2; pool[wv][lane * 4 + 3] = a3;
        }
        __syncthreads();
        const int jj = tid & 255, kh = tid >> 8;
        if (tid < 256) {
            float s = 0.f;
#pragma unroll
            for (int w = 0; w < 8; w++) s += pool[w][tid];
            buf[tid] = s * (1.0f / 256.0f);
        }
        __syncthreads();
        {
            const float* Wcol = W1 + (size_t)(kh * 128) * HD + jj;
            const float* bk = buf + kh * 128;
            float p0 = 0.f, p1 = 0.f, p2 = 0.f, p3 = 0.f;
#pragma unroll
            for (int k = 0; k < 128; k += 4) {
                p0 += bk[k + 0] * Wcol[(size_t)(k + 0) * HD];
                p1 += bk[k + 1] * Wcol[(size_t)(k + 1) * HD];
                p2 += bk[k + 2] * Wcol[(size_t)(k + 2) * HD];
                p3 += bk[k + 3] * Wcol[(size_t)(k + 3) * HD];
            }
            part[kh][jj] = (p0 + p1) + (p2 + p3);
        }
        __syncthreads();
        if (tid < 256) {
            float z = part[0][tid] + part[1][tid] + b1[tid];
            z = (z - m1[tid]) * rsqrtf(v1[tid] + 1e-5f) * g1[tid] + be1[tid];
            buf[tid] = fmaxf(z, 0.f);
        }
        __syncthreads();
        {
            const float* Wcol = W2 + (size_t)(kh * 128) * HD + jj;
            const float* bk = buf + kh * 128;
            float p0 = 0.f, p1 = 0.f, p2 = 0.f, p3 = 0.f;
#pragma unroll
            for (int k = 0; k < 128; k += 4) {
                p0 += bk[k + 0] * Wcol[(size_t)(k + 0) * HD];
                p1 += bk[k + 1] * Wcol[(size_t)(k + 1) * HD];
                p2 += bk[k + 2] * Wcol[(size_t)(k + 2) * HD];
                p3 += bk[k + 3] * Wcol[(size_t)(k + 3) * HD];
            }
            part[kh][jj] = (p0 + p1) + (p2 + p3);
        }
        __syncthreads();
        float pv = 0.f;
        if (tid < 256) {
            float z2 = part[0][tid] + part[1][tid] + b2p[tid];
            z2 = (z2 - m2[tid]) * rsqrtf(v2[tid] + 1e-5f) * g2[tid] + be2[tid];
            z2 = fmaxf(z2, 0.f);
            pv = z2 * Wv[tid];
        }
#pragma unroll
        for (int mm = 1; mm < 64; mm <<= 1) pv += __shfl_xor(pv, mm, 64);
        if (tid < 256 && (tid & 63) == 0) red[tid >> 6] = pv;
        __syncthreads();
        if (tid == 0) vout[g] = tanhf(red[0] + red[1] + red[2] + red[3] + bv[0]);
    }
}

// ---------------- per-move: 8 lanes per move row; coalesced; shfl reduce ----------------
__global__ __launch_bounds__(256) void k_moves(const u16* __restrict__ hP1, const u16* __restrict__ hP2,
                                               const float* __restrict__ wp2, const float* __restrict__ bp2,
                                               const int* __restrict__ mov, float* __restrict__ out) {
    __shared__ float wp2L[256];
    wp2L[threadIdx.x] = wp2[threadIdx.x];
    __syncthreads();
    const int wv = threadIdx.x >> 6, lane = threadIdx.x & 63;
    const int grp = lane >> 3, li = lane & 7;
    const int mi = blockIdx.x * 32 + wv * 8 + grp;
    int a = mov[(size_t)mi * 2], b = mov[(size_t)mi * 2 + 1];
    const bool vld = (a != -1) && (b != -1);
    const int s = a < 0 ? 0 : a, t = b < 0 ? 0 : b;
    const u16* r1 = hP1 + (size_t)s * HD + li * 32;
    const u16* r2 = hP2 + (size_t)t * HD + li * 32;
    float acc = 0.f;
#pragma unroll
    for (int c = 0; c < 4; c++) {
        u16x8 v1 = *(const u16x8*)(r1 + c * 8);
        u16x8 v2 = *(const u16x8*)(r2 + c * 8);
#pragma unroll
        for (int j = 0; j < 8; j++) {
            float z = b2f(v1[j]) + b2f(v2[j]);
            acc += fmaxf(z, 0.f) * wp2L[li * 32 + c * 8 + j];
        }
    }
    acc += __shfl_xor(acc, 1); acc += __shfl_xor(acc, 2); acc += __shfl_xor(acc, 4);
    if (li == 0) out[mi] = vld ? acc + bp2[0] : -1e9f;
}

extern "C" void kernel_launch(void* const* d_in, const int* in_sizes, int n_in,
                              void* d_out, int out_size, void* d_ws, size_t ws_size,
                              hipStream_t stream) {
    const float* x    = (const float*)d_in[0];
    const int* eidx   = (const int*)d_in[1];
    const int* mov    = (const int*)d_in[2];
    const int* player = (const int*)d_in[3];
    const float* Win  = (const float*)d_in[5];
    const float* b_in = (const float*)d_in[6];
    const float* Wg1 = (const float*)d_in[7],  *bg1 = (const float*)d_in[8];
    const float* Wg2 = (const float*)d_in[9],  *bg2 = (const float*)d_in[10];
    const float* Wg3 = (const float*)d_in[11], *bg3 = (const float*)d_in[12];
    const float* ln1g = (const float*)d_in[13], *ln1b = (const float*)d_in[14];
    const float* ln2g = (const float*)d_in[15], *ln2b = (const float*)d_in[16];
    const float* ln3g = (const float*)d_in[17], *ln3b = (const float*)d_in[18];
    const float* Wfc1 = (const float*)d_in[19], *bfc1 = (const float*)d_in[20];
    const float* Wfc2 = (const float*)d_in[21], *bfc2 = (const float*)d_in[22];
    const float* bn1g = (const float*)d_in[23], *bn1b = (const float*)d_in[24];
    const float* bn1m = (const float*)d_in[25], *bn1v = (const float*)d_in[26];
    const float* bn2g = (const float*)d_in[27], *bn2b = (const float*)d_in[28];
    const float* bn2m = (const float*)d_in[29], *bn2v = (const float*)d_in[30];
    const float* Wp1 = (const float*)d_in[31], *bp1 = (const float*)d_in[32];
    const float* Wp2 = (const float*)d_in[33], *bp2 = (const float*)d_in[34];
    const float* Wv  = (const float*)d_in[35], *bv  = (const float*)d_in[36];

    char* ws = (char*)d_ws;
    size_t off = 0;
    auto alloc = [&](size_t bytes) {
        size_t p = off;
        off = (off + bytes + 255) & ~(size_t)255;
        return (void*)(ws + p);
    };
    u16* h0   = (u16*)alloc((size_t)(NN + 8) * HD * 2);
    u16* hA   = (u16*)alloc((size_t)(NN + 8) * HD * 2);
    u16* hB   = (u16*)alloc((size_t)(NN + 8) * HD * 2);
    u16* hin  = (u16*)alloc((size_t)NN * HD * 2);
    u16* Ws1  = (u16*)alloc((size_t)HD * HD * 2);
    u16* Ws2  = (u16*)alloc((size_t)HD * HD * 2);
    u16* Ws3  = (u16*)alloc((size_t)HD * HD * 2);
    u16* Wsa  = (u16*)alloc((size_t)HD * HD * 2);
    u16* Wsb  = (u16*)alloc((size_t)HD * HD * 2);
    int* deg  = (int*)alloc((size_t)NN * 4);
    int* adj  = (int*)alloc((size_t)NN * KADJ * 4);

    const int* esrc = eidx;
    const int* edst = eidx + NE;

    hipMemsetAsync(deg, 0, (size_t)NN * 4, stream);
    k_prep<<<1361, 256, 0, stream>>>(Wg1, Wg2, Wg3, Wp1, Ws1, Ws2, Ws3, Wsa, Wsb,
                                     x, player, Win, b_in, h0, esrc, edst, deg, adj,
                                     h0 + (size_t)NN * HD, hA + (size_t)NN * HD, hB + (size_t)NN * HD);

    // layer 1 (agg sorts adj canonically and writes it back for layers 2/3)
    k_agg<<<NN / 8, 256, 0, stream>>>(h0, deg, adj, hin, 1);
    k_mmln<<<NN / 64, 256, 0, stream>>>(hin, Ws1, bg1, ln1g, ln1b, nullptr, hA);
    // layer 2
    k_agg<<<NN / 8, 256, 0, stream>>>(hA, deg, adj, hin, 0);
    k_mmln<<<NN / 64, 256, 0, stream>>>(hin, Ws2, bg2, ln2g, ln2b, nullptr, hB);
    // layer 3 (+residual)
    k_agg<<<NN / 8, 256, 0, stream>>>(hB, deg, adj, hin, 0);
    k_mmln<<<NN / 64, 256, 0, stream>>>(hin, Ws3, bg3, ln3g, ln3b, h0, hA);

    // h0, hB dead -> reuse for policy precompute
    u16* hP1 = h0;
    u16* hP2 = hB;

    k_densepv<<<1152, 512, 0, stream>>>(hA, Wsa, Wsb, bp1, hP1, hP2,
                                        Wfc1, bfc1, Wfc2, bfc2,
                                        bn1g, bn1b, bn1m, bn1v, bn2g, bn2b, bn2m, bn2v,
                                        Wv, bv, ((float*)d_out) + NB * NM);
    k_moves<<<(NB * NM) / 32, 256, 0, stream>>>(hP1, hP2, Wp2, bp2, mov, (float*)d_out);
}